// Round 6
// baseline (304.146 us; speedup 1.0000x reference)
//
#include <hip/hip_runtime.h>

// Problem: M=65536, K=512, N=512
//   x_scale = max(|x|)/127 (>= 1e-5); x_int8 = clip(rint(x/x_scale));
//   out = (x_int8 @ W^T).f32 * (x_scale * wscale[n])
//
// R11 = R10 minus LDS-B staging, minus stagger.
//   k1 (unchanged): 4096-chunk absmax -> device atomicMax; weight repack.
//   k2: 512 blocks x 256 thr (2/CU). Quant strip -> swizzled LDS -> A frags
//     in regs (proven R6 path). Then ONE barrier and a BARRIER-FREE gemm:
//     B fragments (256 KB total, L2-resident) are loaded directly
//     global->VGPR with the exact addresses the old global_load_lds staging
//     used (bit-identical fragments). No __syncthreads in the gemm phase
//     -> no vmcnt(0) drains -> epilogue stores (128 MB chip-wide) never
//     sit inside a barrier stall; waves free-run and de-phase naturally.
//   Cost: each wave re-reads B (2048 waves x 256 KB = 512 MB L2 reads
//   ~15 us aggregate at 34.5 TB/s), fully overlapped with MFMA + stores.

#define M_DIM 65536
#define K_DIM 512
#define N_DIM 512
#define EPSF  1e-5f

typedef int int32x4 __attribute__((ext_vector_type(4)));

// ---- ws layout (bytes) ----
#define WS_ABS    0                         // 4 B absmax bits (memset to 0)
#define WS_WPACK  32768                     // packed int8 weight (256 KB)

__device__ inline unsigned int pack_w4(int4 v) {
    return (v.x & 0xff) | ((v.y & 0xff) << 8) |
           ((v.z & 0xff) << 16) | ((unsigned)v.w << 24);
}

// quantize 4 floats -> 4 packed int8 (RNE magic constant; no clamp needed
// since |x*inv| <= ~127.00002).
__device__ inline unsigned int quantpack4(float4 f, float inv) {
    const float C = 12582912.0f;  // 1.5 * 2^23
    unsigned int u0 = __float_as_uint(fmaf(f.x, inv, C));
    unsigned int u1 = __float_as_uint(fmaf(f.y, inv, C));
    unsigned int u2 = __float_as_uint(fmaf(f.z, inv, C));
    unsigned int u3 = __float_as_uint(fmaf(f.w, inv, C));
    unsigned int lo = __builtin_amdgcn_perm(u1, u0, 0x0C0C0400u);
    unsigned int hi = __builtin_amdgcn_perm(u3, u2, 0x04000C0Cu);
    return lo | hi;
}

// ---------------- Kernel 1: absmax (atomic) + weight repack (fused grid) ----
__global__ void absmax1_pack_kernel(const float* __restrict__ x,
                                    const int* __restrict__ wi,
                                    unsigned int* __restrict__ ws_abs,
                                    unsigned int* __restrict__ wp) {
    const int b = blockIdx.x;
    const int t = threadIdx.x;
    if (b < 4096) {
        __shared__ float red[4];
        const float4* x4 = (const float4*)x;
        const int base = b * 2048;               // float4 units (32 KB chunk)
        float m = 0.0f;
        #pragma unroll
        for (int j = 0; j < 8; ++j) {
            float4 v = x4[base + j * 256 + t];
            m = fmaxf(m, fmaxf(fmaxf(fabsf(v.x), fabsf(v.y)),
                               fmaxf(fabsf(v.z), fabsf(v.w))));
        }
        #pragma unroll
        for (int off = 32; off > 0; off >>= 1)
            m = fmaxf(m, __shfl_xor(m, off));
        if ((t & 63) == 0) red[t >> 6] = m;
        __syncthreads();
        if (t == 0) {
            float bm = fmaxf(fmaxf(red[0], red[1]), fmaxf(red[2], red[3]));
            atomicMax(ws_abs, __float_as_uint(bm));   // device scope
        }
    } else {
        const int bb = b - 4096;
        #pragma unroll
        for (int j = 0; j < 4; ++j) {
            int d = bb * 1024 + j * 256 + t;     // packed dword index
            wp[d] = pack_w4(((const int4*)wi)[d]);
        }
    }
}

// ---------------- Kernel 2: fused quant + int8 GEMM + dequant --------------
// 512 blocks x 256 threads (4 waves), 2 blocks/CU. Block owns M-strip
// [128*blockIdx, +128). LDS used ONLY for the quant->fragment A handoff;
// gemm phase is barrier-free with B fragments loaded straight from L2.
__global__ __launch_bounds__(256, 2) void quant_gemm_kernel(
    const float* __restrict__ x, const signed char* __restrict__ w,
    const float* __restrict__ wscale, const unsigned int* __restrict__ ws_abs,
    float* __restrict__ out) {
    __shared__ __attribute__((aligned(16))) signed char Lds[64 * 1024];

    const int t    = threadIdx.x;
    const int wave = t >> 6;
    const int lane = t & 63;
    const int quad = lane >> 4;
    const int l16  = lane & 15;
    const int b    = blockIdx.x;
    const int m0   = b * 128;

    // ---- scale from k1's atomic absmax ----
    const float mx  = __uint_as_float(ws_abs[0]);
    const float s   = fmaxf(mx / 127.0f, EPSF);
    const float inv = 1.0f / s;

    // ---- quantize own strip (256 KB fp32, L3-hot) into swizzled A-LDS ----
    // thread t, iter j: 4 consecutive float4 = 16 floats = one 16 B LDS slot
    // at (row = j*8 + t/32, bytecol = (t&31)*16), byte ^= (row&7)<<4.
    {
        const float4* xs = (const float4*)(x + (size_t)m0 * K_DIM);
        const int rsub = t >> 5;
        const int csub = (t & 31) * 16;
        #pragma unroll
        for (int j = 0; j < 16; ++j) {
            const int fi = j * 1024 + t * 4;     // float4 index in strip
            float4 v0 = xs[fi + 0];
            float4 v1 = xs[fi + 1];
            float4 v2 = xs[fi + 2];
            float4 v3 = xs[fi + 3];
            int32x4 p;
            p.x = (int)quantpack4(v0, inv);
            p.y = (int)quantpack4(v1, inv);
            p.z = (int)quantpack4(v2, inv);
            p.w = (int)quantpack4(v3, inv);
            const int row  = j * 8 + rsub;
            const int addr = (row * 512 + csub) ^ ((row & 7) << 4);
            *(int32x4*)(Lds + addr) = p;
        }
    }
    __syncthreads();   // quant writes -> fragment reads handoff (only barrier)

    // ---- A fragments -> registers (64 VGPRs) ----
    int32x4 a0[8], a1[8];
    {
        const int r0 = wave * 32 + l16;
        const int r1 = r0 + 16;
        #pragma unroll
        for (int k = 0; k < 8; ++k) {
            const int c = quad * 16 + k * 64;
            a0[k] = *(const int32x4*)(Lds + ((r0 * 512 + c) ^ ((r0 & 7) << 4)));
            a1[k] = *(const int32x4*)(Lds + ((r1 * 512 + c) ^ ((r1 & 7) << 4)));
        }
    }

    const int mw = m0 + wave * 32;

    // per-lane B base: row l16, k-quad offset. Fragment (bx,tt,k) adds
    // bx*128*512 + tt*16*512 + k*64 (compile-time in the unrolled loop).
    const signed char* wb = w + (long)l16 * K_DIM + quad * 16;

    // ---- barrier-free GEMM over 4 N-tiles ----
    for (int bx = 0; bx < 4; ++bx) {
        const int n0 = bx * 128;
        const signed char* wt = wb + (long)n0 * K_DIM;

        int32x4 acc0[8] = {};
        int32x4 acc1[8] = {};
        #pragma unroll
        for (int k = 0; k < 8; ++k) {
            #pragma unroll
            for (int tt = 0; tt < 8; ++tt) {
                int32x4 bfrag = *(const int32x4*)(wt + (long)tt * 16 * K_DIM + k * 64);
                acc0[tt] = __builtin_amdgcn_mfma_i32_16x16x64_i8(a0[k], bfrag, acc0[tt], 0, 0, 0);
                acc1[tt] = __builtin_amdgcn_mfma_i32_16x16x64_i8(a1[k], bfrag, acc1[tt], 0, 0, 0);
            }
        }

        // epilogue for this N-tile (no barrier anywhere after this)
        #pragma unroll
        for (int tt = 0; tt < 8; ++tt) {
            int n = n0 + tt * 16 + l16;
            float c = s * wscale[n];
            float* o0 = out + (long)(mw + quad * 4) * N_DIM + n;
            float* o1 = o0 + (long)16 * N_DIM;
            #pragma unroll
            for (int r = 0; r < 4; ++r) {
                o0[(long)r * N_DIM] = (float)acc0[tt][r] * c;
                o1[(long)r * N_DIM] = (float)acc1[tt][r] * c;
            }
        }
    }
}

extern "C" void kernel_launch(void* const* d_in, const int* in_sizes, int n_in,
                              void* d_out, int out_size, void* d_ws, size_t ws_size,
                              hipStream_t stream) {
    const float* x   = (const float*)d_in[0];
    const int*   wi  = (const int*)d_in[1];    // int8 values stored as int32
    const float* sc  = (const float*)d_in[2];
    float*       out = (float*)d_out;

    unsigned int* ws_abs = (unsigned int*)d_ws;
    unsigned int* wp     = (unsigned int*)((char*)d_ws + WS_WPACK);
    const signed char* w8 = (const signed char*)wp;

    // zero the absmax cell (graph-capturable memset node)
    hipMemsetAsync(d_ws, 0, 4, stream);

    absmax1_pack_kernel<<<4160, 256, 0, stream>>>(x, wi, ws_abs, wp);
    quant_gemm_kernel<<<512, 256, 0, stream>>>(x, w8, sc, ws_abs, out);
}